// Round 1
// 5141.562 us; speedup vs baseline: 2.4485x; 2.4485x over previous
//
#include <hip/hip_runtime.h>
#include <hip/hip_bf16.h>

#define L 12
#define D 1024
#define H 16
#define DH 64
#define S 512
#define B 4
#define V 16386
#define NT 16
#define M_ROWS (B * S)   // 2048
#define VP 16512         // V padded up to multiple of 128

typedef __attribute__((ext_vector_type(8))) short bf16x8;
typedef __attribute__((ext_vector_type(4))) float f32x4;

__device__ __forceinline__ float bf2f(unsigned short u) {
    union { unsigned int i; float f; } v; v.i = ((unsigned int)u) << 16; return v.f;
}
__device__ __forceinline__ unsigned short f2bf(float f) {   // round-to-nearest-even
    union { unsigned int i; float f; } v; v.f = f;
    unsigned int r = v.i + 0x7fffu + ((v.i >> 16) & 1u);
    return (unsigned short)(r >> 16);
}

typedef const __attribute__((address_space(1))) void* gas1_t;
typedef __attribute__((address_space(3))) void* las3_t;
__device__ __forceinline__ void gl_lds16(const void* g, void* l) {
    __builtin_amdgcn_global_load_lds((gas1_t)g, (las3_t)l, 16, 0, 0);
}

// ---------------------------------------------------------------- embedding
__global__ __launch_bounds__(256) void embed_kernel(
    const int* __restrict__ ids, const int* __restrict__ tts,
    const float* __restrict__ wte, const float* __restrict__ wtte,
    const float* __restrict__ wpe, float* __restrict__ h)
{
    int row = blockIdx.x;            // b*S + s
    int s = row % S;
    int id = ids[row], tt = tts[row];
    int c = threadIdx.x * 4;
    const float4 a = *(const float4*)(wte  + (size_t)id * D + c);
    const float4 p = *(const float4*)(wpe  + (size_t)s  * D + c);
    const float4 t = *(const float4*)(wtte + (size_t)tt * D + c);
    float4 r;
    r.x = a.x + p.x + t.x; r.y = a.y + p.y + t.y;
    r.z = a.z + p.z + t.z; r.w = a.w + p.w + t.w;
    *(float4*)(h + (size_t)row * D + c) = r;
}

// ---------------------------------------------------------------- layernorm (fp32 in, bf16 out)
__global__ __launch_bounds__(256) void ln_kernel(
    const float* __restrict__ x, const float* __restrict__ w,
    const float* __restrict__ b, unsigned short* __restrict__ y)
{
    int row = blockIdx.x;
    int c = threadIdx.x * 4;
    const float* xr = x + (size_t)row * D;
    float4 v = *(const float4*)(xr + c);
    float s  = v.x + v.y + v.z + v.w;
    float ss = v.x*v.x + v.y*v.y + v.z*v.z + v.w*v.w;
    for (int off = 32; off; off >>= 1) {
        s  += __shfl_xor(s, off);
        ss += __shfl_xor(ss, off);
    }
    __shared__ float sm[8];
    int lane = threadIdx.x & 63, wv = threadIdx.x >> 6;
    if (lane == 0) { sm[wv] = s; sm[4 + wv] = ss; }
    __syncthreads();
    s  = sm[0] + sm[1] + sm[2] + sm[3];
    ss = sm[4] + sm[5] + sm[6] + sm[7];
    float mu  = s * (1.0f / D);
    float var = ss * (1.0f / D) - mu * mu;
    float rstd = rsqrtf(var + 1e-5f);
    float4 wv4 = *(const float4*)(w + c);
    float4 bv4 = *(const float4*)(b + c);
    ushort4 o;
    o.x = f2bf((v.x - mu) * rstd * wv4.x + bv4.x);
    o.y = f2bf((v.y - mu) * rstd * wv4.y + bv4.y);
    o.z = f2bf((v.z - mu) * rstd * wv4.z + bv4.z);
    o.w = f2bf((v.w - mu) * rstd * wv4.w + bv4.w);
    *(ushort4*)(y + (size_t)row * D + c) = o;
}

// ------------------------------------------------- weight transpose + bf16 convert
// W fp32 [K][N]  ->  WT bf16 [N(pad)][K].  Pad rows (n >= N) are zeroed.
__global__ __launch_bounds__(256) void trans_kernel(
    const float* __restrict__ W, unsigned short* __restrict__ WT, int K, int N)
{
    __shared__ unsigned short T[64][72];
    int n0 = blockIdx.x * 64, k0 = blockIdx.y * 64;
    int tid = threadIdx.x;
    int kr = tid >> 4;            // 0..15
    int nc = (tid & 15) * 4;
    bool fullN = (n0 + 64 <= N);
#pragma unroll
    for (int p = 0; p < 4; ++p) {
        int k = p * 16 + kr;
        float4 v;
        if (fullN) {
            v = *(const float4*)(W + (size_t)(k0 + k) * N + n0 + nc);
        } else {
            float* pv = (float*)&v;
            for (int j = 0; j < 4; ++j) {
                int n = n0 + nc + j;
                pv[j] = (n < N) ? W[(size_t)(k0 + k) * N + n] : 0.0f;
            }
        }
        ushort4 u;
        u.x = f2bf(v.x); u.y = f2bf(v.y); u.z = f2bf(v.z); u.w = f2bf(v.w);
        *(ushort4*)&T[k][nc] = u;
    }
    __syncthreads();
    int nr = tid >> 4, kc = (tid & 15) * 4;
#pragma unroll
    for (int p = 0; p < 4; ++p) {
        int n = p * 16 + nr;
        ushort4 u;
        u.x = T[kc + 0][n]; u.y = T[kc + 1][n];
        u.z = T[kc + 2][n]; u.w = T[kc + 3][n];
        *(ushort4*)(WT + (size_t)(n0 + n) * K + k0 + kc) = u;
    }
}

// ---------------------------------------------------------------- MFMA GEMM
// C[M][N] = A[M][K](bf16) x W (via Bt = W^T [N][K] bf16) + bias, optional gelu,
// optional fp32 residual; output fp32 (Cf) or bf16 (Cb).
// 128x128 tile, BK=32, 4 waves x (4x4 16x16 frags). global_load_lds staging with
// pre-swizzled source (slot g ^= (row>>1)&3) -> bank-balanced swizzled ds_read_b128.
__device__ __forceinline__ float gelu_new(float x)
{
    float a = 0.7978845608028654f * (x + 0.044715f * x * x * x);
    float e = __expf(-2.0f * fabsf(a));
    float t = (1.0f - e) / (1.0f + e);
    t = (a >= 0.0f) ? t : -t;
    return 0.5f * x * (1.0f + t);
}

__global__ __launch_bounds__(256) void mfma_gemm(
    const unsigned short* __restrict__ A, const unsigned short* __restrict__ Bt,
    const float* __restrict__ bias, const float* __restrict__ res,
    float* __restrict__ Cf, unsigned short* __restrict__ Cb,
    int N, int K, int dogelu)
{
    __shared__ unsigned short As[128 * 32];   // 8 KB
    __shared__ unsigned short Bs[128 * 32];   // 8 KB

    int tid = threadIdx.x;
    int lane = tid & 63;
    int w = tid >> 6;
    int wr = w >> 1, wc = w & 1;
    int bm = blockIdx.y * 128;
    int bn = blockIdx.x * 128;

    // staging: slot s in [0,512): row = s>>2, LDS slot k16 = s&3 holds global
    // 16B-chunk g = k16 ^ ((row>>1)&3).  LDS dest is linear (slot*16 bytes).
    int s0 = tid, s1 = tid + 256;
    const unsigned short* ga0 = A  + (size_t)(bm + (s0 >> 2)) * K + (((s0 & 3) ^ ((s0 >> 3) & 3)) << 3);
    const unsigned short* ga1 = A  + (size_t)(bm + (s1 >> 2)) * K + (((s1 & 3) ^ ((s1 >> 3) & 3)) << 3);
    const unsigned short* gb0 = Bt + (size_t)(bn + (s0 >> 2)) * K + (((s0 & 3) ^ ((s0 >> 3) & 3)) << 3);
    const unsigned short* gb1 = Bt + (size_t)(bn + (s1 >> 2)) * K + (((s1 & 3) ^ ((s1 >> 3) & 3)) << 3);
    unsigned short* lA0 = &As[(w * 64) * 8];          // wave-uniform LDS bases
    unsigned short* lA1 = &As[(256 + w * 64) * 8];
    unsigned short* lB0 = &Bs[(w * 64) * 8];
    unsigned short* lB1 = &Bs[(256 + w * 64) * 8];

    int rl = lane & 15, gl = lane >> 4;
    int swz = (gl ^ ((rl >> 1) & 3)) << 3;            // short offset of 16B chunk
    int aoff[4], boff[4];
#pragma unroll
    for (int m = 0; m < 4; ++m) aoff[m] = (wr * 64 + m * 16 + rl) * 32 + swz;
#pragma unroll
    for (int n = 0; n < 4; ++n) boff[n] = (wc * 64 + n * 16 + rl) * 32 + swz;

    f32x4 zero = {0.f, 0.f, 0.f, 0.f};
    f32x4 acc[4][4];
#pragma unroll
    for (int m = 0; m < 4; ++m)
#pragma unroll
        for (int n = 0; n < 4; ++n) acc[m][n] = zero;

    for (int k0 = 0; k0 < K; k0 += 32) {
        gl_lds16(ga0 + k0, lA0);
        gl_lds16(ga1 + k0, lA1);
        gl_lds16(gb0 + k0, lB0);
        gl_lds16(gb1 + k0, lB1);
        __syncthreads();                               // compiler drains vmcnt here

        bf16x8 aF[4], bF[4];
#pragma unroll
        for (int m = 0; m < 4; ++m) aF[m] = *(const bf16x8*)&As[aoff[m]];
#pragma unroll
        for (int n = 0; n < 4; ++n) bF[n] = *(const bf16x8*)&Bs[boff[n]];
#pragma unroll
        for (int m = 0; m < 4; ++m)
#pragma unroll
            for (int n = 0; n < 4; ++n)
                acc[m][n] = __builtin_amdgcn_mfma_f32_16x16x32_bf16(
                    aF[m], bF[n], acc[m][n], 0, 0, 0);
        __syncthreads();
    }

    // C/D layout: col = lane&15, row = (lane>>4)*4 + j  (guide m89, HW-verified)
    int cl = lane & 15, rg = lane >> 4;
#pragma unroll
    for (int m = 0; m < 4; ++m) {
        int r0 = bm + wr * 64 + m * 16 + rg * 4;
#pragma unroll
        for (int n = 0; n < 4; ++n) {
            int col = bn + wc * 64 + n * 16 + cl;
            if (col < N) {
                float bv = bias[col];
#pragma unroll
                for (int j = 0; j < 4; ++j) {
                    float v2 = acc[m][n][j] + bv;
                    if (dogelu) v2 = gelu_new(v2);
                    size_t idx = (size_t)(r0 + j) * N + col;
                    if (res) v2 += res[idx];
                    if (Cf) Cf[idx] = v2;
                    else    Cb[idx] = f2bf(v2);
                }
            }
        }
    }
}

// ---------------------------------------------------------------- attention
// Flash-style fp32 compute, bf16 qkv in / bf16 o out.
#define QT 64
#define KT 64
#define APAD 68

__global__ __launch_bounds__(256) void attn_kernel(
    const unsigned short* __restrict__ qkv, unsigned short* __restrict__ o)
{
    __shared__ float Qs[QT][APAD];
    __shared__ float Ks[KT][APAD];
    __shared__ float Vs[KT][APAD];
    __shared__ float Ps[QT][APAD];

    int tid = threadIdx.x;
    int bh = blockIdx.y;           // b*H + h
    int b = bh >> 4, hh = bh & 15;
    int qt = blockIdx.x;

    const size_t rs = 3 * D;
    const unsigned short* qb = qkv + (size_t)(b * S) * rs + hh * DH;
    const unsigned short* kb = qb + D;
    const unsigned short* vb = qb + 2 * D;

    int lr = tid >> 4;
    int lc = (tid & 15) * 4;

#pragma unroll
    for (int p = 0; p < 4; ++p) {
        int r = p * 16 + lr;
        ushort4 u = *(const ushort4*)(qb + (size_t)(qt * QT + r) * rs + lc);
        float4 v;
        v.x = bf2f(u.x) * 0.125f; v.y = bf2f(u.y) * 0.125f;
        v.z = bf2f(u.z) * 0.125f; v.w = bf2f(u.w) * 0.125f;
        *(float4*)&Qs[r][lc] = v;
    }

    int tr = tid >> 4;
    int tc = tid & 15;

    float acc[4][4] = {};
    float mrun[4] = {-1e30f, -1e30f, -1e30f, -1e30f};
    float lrun[4] = {0.f, 0.f, 0.f, 0.f};

    for (int kt = 0; kt <= qt; ++kt) {
        __syncthreads();
#pragma unroll
        for (int p = 0; p < 4; ++p) {
            int r = p * 16 + lr;
            ushort4 uk = *(const ushort4*)(kb + (size_t)(kt * KT + r) * rs + lc);
            ushort4 uv = *(const ushort4*)(vb + (size_t)(kt * KT + r) * rs + lc);
            float4 kv4, vv4;
            kv4.x = bf2f(uk.x); kv4.y = bf2f(uk.y); kv4.z = bf2f(uk.z); kv4.w = bf2f(uk.w);
            vv4.x = bf2f(uv.x); vv4.y = bf2f(uv.y); vv4.z = bf2f(uv.z); vv4.w = bf2f(uv.w);
            *(float4*)&Ks[r][lc] = kv4;
            *(float4*)&Vs[r][lc] = vv4;
        }
        __syncthreads();

        float s[4][4] = {};
#pragma unroll
        for (int d = 0; d < DH; d += 4) {
            float4 qv[4], kv[4];
#pragma unroll
            for (int i = 0; i < 4; ++i) qv[i] = *(const float4*)&Qs[tr * 4 + i][d];
#pragma unroll
            for (int j = 0; j < 4; ++j) kv[j] = *(const float4*)&Ks[tc + 16 * j][d];
#pragma unroll
            for (int i = 0; i < 4; ++i)
#pragma unroll
                for (int j = 0; j < 4; ++j)
                    s[i][j] += qv[i].x * kv[j].x + qv[i].y * kv[j].y
                             + qv[i].z * kv[j].z + qv[i].w * kv[j].w;
        }

        bool diag = (kt == qt);
#pragma unroll
        for (int i = 0; i < 4; ++i) {
            int qrow = qt * QT + tr * 4 + i;
            if (diag) {
#pragma unroll
                for (int j = 0; j < 4; ++j) {
                    int kcol = kt * KT + tc + 16 * j;
                    if (kcol > qrow) s[i][j] = -1e30f;
                }
            }
            float rmax = fmaxf(fmaxf(s[i][0], s[i][1]), fmaxf(s[i][2], s[i][3]));
#pragma unroll
            for (int off = 8; off; off >>= 1) rmax = fmaxf(rmax, __shfl_xor(rmax, off));
            float newm = fmaxf(mrun[i], rmax);
            float alpha = __expf(mrun[i] - newm);
            mrun[i] = newm;
            float pj[4], rsum = 0.f;
#pragma unroll
            for (int j = 0; j < 4; ++j) { pj[j] = __expf(s[i][j] - newm); rsum += pj[j]; }
#pragma unroll
            for (int off = 8; off; off >>= 1) rsum += __shfl_xor(rsum, off);
            lrun[i] = lrun[i] * alpha + rsum;
#pragma unroll
            for (int j = 0; j < 4; ++j) {
                acc[i][j] *= alpha;
                Ps[tr * 4 + i][tc + 16 * j] = pj[j];
            }
        }
        __syncthreads();

#pragma unroll
        for (int k = 0; k < KT; k += 4) {
            float4 pv[4], vv[4];
#pragma unroll
            for (int i = 0; i < 4; ++i) pv[i] = *(const float4*)&Ps[tr * 4 + i][k];
#pragma unroll
            for (int u = 0; u < 4; ++u) vv[u] = *(const float4*)&Vs[k + u][tc * 4];
#pragma unroll
            for (int i = 0; i < 4; ++i) {
                const float* pi = (const float*)&pv[i];
#pragma unroll
                for (int j = 0; j < 4; ++j) {
                    const float* v0 = (const float*)&vv[0];
                    const float* v1 = (const float*)&vv[1];
                    const float* v2 = (const float*)&vv[2];
                    const float* v3 = (const float*)&vv[3];
                    acc[i][j] += pi[0] * v0[j] + pi[1] * v1[j]
                               + pi[2] * v2[j] + pi[3] * v3[j];
                }
            }
        }
    }

#pragma unroll
    for (int i = 0; i < 4; ++i) {
        float inv = 1.0f / lrun[i];
        int qrow = qt * QT + tr * 4 + i;
        ushort4 ov;
        ov.x = f2bf(acc[i][0] * inv); ov.y = f2bf(acc[i][1] * inv);
        ov.z = f2bf(acc[i][2] * inv); ov.w = f2bf(acc[i][3] * inv);
        *(ushort4*)(o + (size_t)(b * S + qrow) * D + hh * DH + tc * 4) = ov;
    }
}

// ---------------------------------------------------------------- launch
extern "C" void kernel_launch(void* const* d_in, const int* in_sizes, int n_in,
                              void* d_out, int out_size, void* d_ws, size_t ws_size,
                              hipStream_t stream)
{
    const int*   ids    = (const int*)d_in[0];
    const int*   tts    = (const int*)d_in[1];
    const float* wte    = (const float*)d_in[2];
    const float* wtte   = (const float*)d_in[3];
    const float* wpe    = (const float*)d_in[4];
    const float* ln1_w  = (const float*)d_in[5];
    const float* ln1_b  = (const float*)d_in[6];
    const float* attn_w = (const float*)d_in[7];
    const float* attn_b = (const float*)d_in[8];
    const float* atp_w  = (const float*)d_in[9];
    const float* atp_b  = (const float*)d_in[10];
    const float* ln2_w  = (const float*)d_in[11];
    const float* ln2_b  = (const float*)d_in[12];
    const float* fc_w   = (const float*)d_in[13];
    const float* fc_b   = (const float*)d_in[14];
    const float* mlp_w  = (const float*)d_in[15];
    const float* mlp_b  = (const float*)d_in[16];
    const float* lnf_w  = (const float*)d_in[17];
    const float* lnf_b  = (const float*)d_in[18];
    const float* head_w = (const float*)d_in[19];
    const float* head_b = (const float*)d_in[20];
    float* out = (float*)d_out;

    // workspace layout (77.8 MB total; previous kernel proved >= 84 MB exists)
    float*          h   = (float*)d_ws;                          // 2048*1024 f32   8 MB
    unsigned short* x   = (unsigned short*)(h + (size_t)M_ROWS * D);   // bf16  4 MB
    unsigned short* qkv = x   + (size_t)M_ROWS * D;              // bf16 [2048][3072] 12 MB
    unsigned short* o   = qkv + (size_t)M_ROWS * 3 * D;          // bf16  4 MB
    unsigned short* m1  = o   + (size_t)M_ROWS * D;              // bf16 [2048][4096] 16 MB
    unsigned short* wT  = m1  + (size_t)M_ROWS * 4 * D;          // bf16 [16512][1024] 33.8 MB

    embed_kernel<<<M_ROWS, 256, 0, stream>>>(ids, tts, wte, wtte, wpe, h);

    for (int l = 0; l < L; ++l) {
        ln_kernel<<<M_ROWS, 256, 0, stream>>>(h, ln1_w + l * D, ln1_b + l * D, x);

        trans_kernel<<<dim3(3 * D / 64, D / 64), 256, 0, stream>>>(
            attn_w + (size_t)l * D * 3 * D, wT, D, 3 * D);
        mfma_gemm<<<dim3(3 * D / 128, M_ROWS / 128), 256, 0, stream>>>(
            x, wT, attn_b + (size_t)l * 3 * D, nullptr, nullptr, qkv, 3 * D, D, 0);

        attn_kernel<<<dim3(S / QT, B * H), 256, 0, stream>>>(qkv, o);

        trans_kernel<<<dim3(D / 64, D / 64), 256, 0, stream>>>(
            atp_w + (size_t)l * D * D, wT, D, D);
        mfma_gemm<<<dim3(D / 128, M_ROWS / 128), 256, 0, stream>>>(
            o, wT, atp_b + (size_t)l * D, h, h, nullptr, D, D, 0);

        ln_kernel<<<M_ROWS, 256, 0, stream>>>(h, ln2_w + l * D, ln2_b + l * D, x);

        trans_kernel<<<dim3(4 * D / 64, D / 64), 256, 0, stream>>>(
            fc_w + (size_t)l * D * 4 * D, wT, D, 4 * D);
        mfma_gemm<<<dim3(4 * D / 128, M_ROWS / 128), 256, 0, stream>>>(
            x, wT, fc_b + (size_t)l * 4 * D, nullptr, nullptr, m1, 4 * D, D, 1);

        trans_kernel<<<dim3(D / 64, 4 * D / 64), 256, 0, stream>>>(
            mlp_w + (size_t)l * 4 * D * D, wT, 4 * D, D);
        mfma_gemm<<<dim3(D / 128, M_ROWS / 128), 256, 0, stream>>>(
            m1, wT, mlp_b + (size_t)l * D, h, h, nullptr, D, 4 * D, 0);
    }

    ln_kernel<<<M_ROWS, 256, 0, stream>>>(h, lnf_w, lnf_b, x);

    trans_kernel<<<dim3(VP / 64, D / 64), 256, 0, stream>>>(head_w, wT, D, V);
    mfma_gemm<<<dim3(VP / 128, M_ROWS / 128), 256, 0, stream>>>(
        x, wT, head_b, nullptr, out, nullptr, V, D, 0);
}